// Round 16
// baseline (2502.090 us; speedup 1.0000x reference)
//
#include <hip/hip_runtime.h>

#define N_ATOMS 100000
#define N_BONDS 200000
#define MAX_NB 6
#define HIDDEN 256
#define DEPTH 6
#define ATOM_FDIM 39
#define BOND_FDIM 11
#define WNODE_COLS (HIDDEN + BOND_FDIM)  // 267

typedef __attribute__((ext_vector_type(8))) short bf16x8;
typedef __attribute__((ext_vector_type(4))) short s16x4;
typedef __attribute__((ext_vector_type(4))) float f32x4;

__device__ __forceinline__ unsigned short f2bf(float x) {
  unsigned u = __float_as_uint(x);
  unsigned r = (u + 0x7FFFu + ((u >> 16) & 1u)) >> 16;
  return (unsigned short)r;
}
__device__ __forceinline__ float bf2f(unsigned short h) {
  return __uint_as_float(((unsigned)h) << 16);
}
// exact 3-term decomposition: x = t1 + t2 + t3 + O(2^-27 x)
__device__ __forceinline__ void split3(float x, short* s1, short* s2, short* s3) {
  unsigned short h1 = f2bf(x);
  float r1 = x - bf2f(h1);
  unsigned short h2 = f2bf(r1);
  float r2 = r1 - bf2f(h2);
  *s1 = (short)h1;
  *s2 = (short)h2;
  *s3 = (short)f2bf(r2);
}

union U4 { short s[4]; s16x4 v; };

// ---------------------------------------------------------------------------
// split_w: one-off. Bsp[t][n][k] = term t of split3(W_node[n][k]), k<256.
// ---------------------------------------------------------------------------
__global__ __launch_bounds__(256) void split_w_kernel(
    const float* __restrict__ W, short* __restrict__ Bsp) {
  int g = blockIdx.x * 256 + threadIdx.x;  // 16384
  int n = g >> 6;
  int k4 = (g & 63) * 4;
  const float* wp = &W[(size_t)n * WNODE_COLS + k4];
  int o = n * 256 + k4;
#pragma unroll
  for (int j = 0; j < 4; ++j) {
    short a, b, c;
    split3(wp[j], &a, &b, &c);
    Bsp[o + j] = a;
    Bsp[65536 + o + j] = b;
    Bsp[131072 + o + j] = c;
  }
}

// ---------------------------------------------------------------------------
// init: per block of 32 atoms (256 thr):
//   Hn = h0 = relu(fatoms @ W_nin.T)   (fp32)
//   base = h0 + (sum_nb fbonds[aoutgraph]) @ W_f.T   (fp32)
// ---------------------------------------------------------------------------
__global__ __launch_bounds__(256) void init_kernel(
    const float* __restrict__ fatoms,
    const float* __restrict__ fbonds,
    const int* __restrict__ aoutgraph,
    const float* __restrict__ W_nin,
    const float* __restrict__ W_node,
    float* __restrict__ Hn,
    float* __restrict__ base) {
  __shared__ float Wn_lds[ATOM_FDIM * 256];   // [k][n]
  __shared__ float Wf_lds[BOND_FDIM * 256];   // [k][n]
  __shared__ float fa_lds[32 * 40];           // [atom][k]
  __shared__ float fs_lds[32 * 12];           // [atom][f]
  int tid = threadIdx.x;
  int a0 = blockIdx.x * 32;

  for (int k = 0; k < ATOM_FDIM; ++k)
    Wn_lds[k * 256 + tid] = W_nin[tid * ATOM_FDIM + k];
  for (int k = 0; k < BOND_FDIM; ++k)
    Wf_lds[k * 256 + tid] = W_node[tid * WNODE_COLS + HIDDEN + k];
  {
    int a_l = tid >> 3, j8 = tid & 7;
#pragma unroll
    for (int jj = 0; jj < 5; ++jj) {
      int k = j8 * 5 + jj;
      if (k < ATOM_FDIM)
        fa_lds[a_l * 40 + k] = fatoms[(size_t)(a0 + a_l) * ATOM_FDIM + k];
    }
  }
  for (int i = tid; i < 384; i += 256) {
    int a_l = i / 12, f = i - a_l * 12;
    if (f < BOND_FDIM) {
      float s = 0.f;
#pragma unroll
      for (int nb = 0; nb < MAX_NB; ++nb) {
        int b = aoutgraph[(size_t)(a0 + a_l) * MAX_NB + nb];
        s += fbonds[(size_t)b * BOND_FDIM + f];
      }
      fs_lds[a_l * 12 + f] = s;
    }
  }
  __syncthreads();

  int l = tid & 63, w = tid >> 6;
  f32x4 acc1[8] = {};
  f32x4 acc2[8] = {};
  for (int k = 0; k < ATOM_FDIM; ++k) {
    f32x4 wv = *(const f32x4*)&Wn_lds[k * 256 + l * 4];
#pragma unroll
    for (int ai = 0; ai < 8; ++ai) {
      float av = fa_lds[(w * 8 + ai) * 40 + k];
      acc1[ai] += wv * av;
    }
  }
  for (int k = 0; k < BOND_FDIM; ++k) {
    f32x4 wv = *(const f32x4*)&Wf_lds[k * 256 + l * 4];
#pragma unroll
    for (int ai = 0; ai < 8; ++ai) {
      float av = fs_lds[(w * 8 + ai) * 12 + k];
      acc2[ai] += wv * av;
    }
  }
#pragma unroll
  for (int ai = 0; ai < 8; ++ai) {
    int a_g = a0 + w * 8 + ai;
    size_t off = (size_t)a_g * HIDDEN + l * 4;
    f32x4 h0v, bs;
#pragma unroll
    for (int j = 0; j < 4; ++j) {
      float h0j = fmaxf(acc1[ai][j], 0.f);
      h0v[j] = h0j;
      bs[j] = h0j + acc2[ai][j];
    }
    *(f32x4*)&Hn[off] = h0v;
    *(f32x4*)&base[off] = bs;
  }
}

// ---------------------------------------------------------------------------
// fused iteration: Hn_out = relu(base + (sum_nb [b!=0] Hn_in[src]) @ W_h.T)
// block = 32 atoms x 256 cols; 256 thr (4 waves; wave w = 32 x cols w*64..+63).
// Issue order per chunk (pinned): B loads (L2-hot, oldest) -> gather loads
// c+1 (young, in flight over MFMA) -> MFMA -> sum/split/ds_write -> barrier.
// Cache policy (r10-proven): normal loads; Hn_out NT store preceded by base
// load (line-merge). THIS ROUND: __launch_bounds__(256,4) -- unified reg use
// ~116 fits the 128/wave budget, unlocking 16 waves/CU of cross-block TLP.
// ---------------------------------------------------------------------------
#define KCH 32
#define AST 40  // LDS row stride in bf16 (32 + 8 pad; 80 B, 16B-aligned)

__global__ __launch_bounds__(256, 4) void fused_kernel(
    const float* __restrict__ Hn_in,
    const float* __restrict__ base,
    const short* __restrict__ Bsp,        // [3][256][256] bf16 terms
    const int* __restrict__ aout,
    const int* __restrict__ bonds,
    float* __restrict__ Hn_out) {
  __shared__ short As[2][3][32 * AST];    // 15.4 KB
  __shared__ int src_lds[192];
  int tid = threadIdx.x;
  int a0 = blockIdx.x * 32;

  if (tid < 192) {
    int a_l = tid / 6, nb = tid - a_l * 6;
    int b = aout[(size_t)(a0 + a_l) * MAX_NB + nb];
    src_lds[tid] = (b != 0) ? bonds[2 * b + 1] : -1;
  }
  __syncthreads();

  int lane = tid & 63, w = tid >> 6;
  int lr = lane & 15, lk = lane >> 4;
  int r_a = tid >> 3, q = tid & 7;        // staging: row 0..31, k-quad 0..7

  // per-thread gather sources as u32 byte offsets from Hn_in (saddr form)
  const char* hb = (const char*)Hn_in;
  unsigned voff[MAX_NB];
  float gw[MAX_NB];
#pragma unroll
  for (int nb = 0; nb < MAX_NB; ++nb) {
    int s = src_lds[r_a * 6 + nb];
    int sr = s >= 0 ? s : 0;
    gw[nb] = s >= 0 ? 1.f : 0.f;
    voff[nb] = (unsigned)((sr * HIDDEN + q * 4) * 4);
  }
  int ao_st = r_a * AST + q * 4;          // LDS write slot (8 B)

  f32x4 acc[2][4] = {};

  // ---- prologue: gather+split chunk 0 into As[0] ----
  {
    f32x4 v = {0.f, 0.f, 0.f, 0.f};
#pragma unroll
    for (int nb = 0; nb < MAX_NB; ++nb)
      v += *(const f32x4*)(hb + voff[nb]) * gw[nb];
    U4 t1, t2, t3;
#pragma unroll
    for (int j = 0; j < 4; ++j) split3(v[j], &t1.s[j], &t2.s[j], &t3.s[j]);
    *(s16x4*)&As[0][0][ao_st] = t1.v;
    *(s16x4*)&As[0][1][ao_st] = t2.v;
    *(s16x4*)&As[0][2][ao_st] = t3.v;
  }
  __syncthreads();

#pragma unroll
  for (int c = 0; c < 8; ++c) {
    const int cur = c & 1;
    // ---- 1. B loads chunk c: issued FIRST -> oldest in vmcnt queue ----
    bf16x8 b0[4], b1[4], b2[4];
#pragma unroll
    for (int n = 0; n < 4; ++n) {
      int bo = (w * 64 + n * 16 + lr) * 256 + c * KCH + lk * 8;
      b0[n] = *(const bf16x8*)&Bsp[bo];
      b1[n] = *(const bf16x8*)&Bsp[65536 + bo];
      b2[n] = *(const bf16x8*)&Bsp[131072 + bo];
    }
    // ---- 2. gather loads chunk c+1: younger, in flight over MFMA ----
    f32x4 ga[MAX_NB];
    if (c < 7) {
#pragma unroll
      for (int nb = 0; nb < MAX_NB; ++nb)
        ga[nb] = *(const f32x4*)(hb + voff[nb] + (c + 1) * KCH * 4);
    }
    __builtin_amdgcn_sched_barrier(0);
    // ---- 3. MFMA cluster: 2 m-frags x 4 n-frags x 6 products ----
    __builtin_amdgcn_s_setprio(1);
#pragma unroll
    for (int m = 0; m < 2; ++m) {
      int ao = (m * 16 + lr) * AST + lk * 8;
      bf16x8 af0 = *(const bf16x8*)&As[cur][0][ao];
      bf16x8 af1 = *(const bf16x8*)&As[cur][1][ao];
      bf16x8 af2 = *(const bf16x8*)&As[cur][2][ao];
#pragma unroll
      for (int n = 0; n < 4; ++n) {
        f32x4 cc = acc[m][n];
        cc = __builtin_amdgcn_mfma_f32_16x16x32_bf16(af0, b0[n], cc, 0, 0, 0);
        cc = __builtin_amdgcn_mfma_f32_16x16x32_bf16(af0, b1[n], cc, 0, 0, 0);
        cc = __builtin_amdgcn_mfma_f32_16x16x32_bf16(af1, b0[n], cc, 0, 0, 0);
        cc = __builtin_amdgcn_mfma_f32_16x16x32_bf16(af1, b1[n], cc, 0, 0, 0);
        cc = __builtin_amdgcn_mfma_f32_16x16x32_bf16(af0, b2[n], cc, 0, 0, 0);
        cc = __builtin_amdgcn_mfma_f32_16x16x32_bf16(af2, b0[n], cc, 0, 0, 0);
        acc[m][n] = cc;
      }
    }
    __builtin_amdgcn_s_setprio(0);
    // ---- 4. finish gather c+1: sum, split, LDS write, barrier ----
    if (c < 7) {
      f32x4 v = {0.f, 0.f, 0.f, 0.f};
#pragma unroll
      for (int nb = 0; nb < MAX_NB; ++nb) v += ga[nb] * gw[nb];
      U4 t1, t2, t3;
#pragma unroll
      for (int j = 0; j < 4; ++j) split3(v[j], &t1.s[j], &t2.s[j], &t3.s[j]);
      *(s16x4*)&As[cur ^ 1][0][ao_st] = t1.v;
      *(s16x4*)&As[cur ^ 1][1][ao_st] = t2.v;
      *(s16x4*)&As[cur ^ 1][2][ao_st] = t3.v;
      __syncthreads();
    }
  }

  // ---- epilogue: relu(base + acc) -> Hn_out (NT store; normal base load
  // precedes the store so lines merge in L2 -- r10/r12 A-B lesson) ----
#pragma unroll
  for (int m = 0; m < 2; ++m) {
    int row0 = a0 + m * 16 + lk * 4;
#pragma unroll
    for (int n = 0; n < 4; ++n) {
      int col = w * 64 + n * 16 + lr;
#pragma unroll
      for (int r = 0; r < 4; ++r) {
        size_t off = (size_t)(row0 + r) * HIDDEN + col;
        float v = fmaxf(base[off] + acc[m][n][r], 0.f);
        __builtin_nontemporal_store(v, &Hn_out[off]);
      }
    }
  }
}

// ---------------------------------------------------------------------------
// transpose: out[h][a] = Hn[a][h]; 64x64 tiles; NT output stores.
// ---------------------------------------------------------------------------
__global__ __launch_bounds__(256) void transpose_kernel(
    const float* __restrict__ Hn, float* __restrict__ out) {
  __shared__ float tile[64][68];
  int a0 = blockIdx.x * 64, h0 = blockIdx.y * 64;
  int tid = threadIdx.x;
#pragma unroll
  for (int p = 0; p < 2; ++p) {
    int id = tid + p * 256;
    int r = id >> 3, c8 = (id & 7) * 8;
    int ag = a0 + r;
    if (ag > N_ATOMS - 1) ag = N_ATOMS - 1;
    const float* hp = &Hn[(size_t)ag * HIDDEN + h0 + c8];
    *(f32x4*)&tile[r][c8] = *(const f32x4*)hp;
    *(f32x4*)&tile[r][c8 + 4] = *(const f32x4*)(hp + 4);
  }
  __syncthreads();
  int h = tid >> 2, as = (tid & 3) * 16;
  size_t ob = (size_t)(h0 + h) * N_ATOMS + a0 + as;
  if (a0 + 64 <= N_ATOMS) {
#pragma unroll
    for (int q = 0; q < 4; ++q) {
      f32x4 v;
#pragma unroll
      for (int j = 0; j < 4; ++j) v[j] = tile[as + q * 4 + j][h];
      __builtin_nontemporal_store(v, (f32x4*)&out[ob + q * 4]);
    }
  } else {
    for (int j = 0; j < 16; ++j)
      if (a0 + as + j < N_ATOMS)
        __builtin_nontemporal_store(tile[as + j][h], &out[ob + j]);
  }
}

extern "C" void kernel_launch(void* const* d_in, const int* in_sizes, int n_in,
                              void* d_out, int out_size, void* d_ws, size_t ws_size,
                              hipStream_t stream) {
  const float* fatoms = (const float*)d_in[0];
  const float* fbonds = (const float*)d_in[1];
  const int* aoutgraph = (const int*)d_in[2];
  const int* all_bonds = (const int*)d_in[3];
  const float* W_nin = (const float*)d_in[4];
  const float* W_node = (const float*)d_in[5];
  float* out = (float*)d_out;

  const size_t NH = (size_t)N_ATOMS * HIDDEN;
  float* base = (float*)d_ws;        // 102.4 MB
  float* HnA = base + NH;            // 102.4 MB
  short* Bsp = (short*)(HnA + NH);   // 384 KB pre-split W terms
  float* HnB = out;                  // d_out doubles as ping-pong buffer

  split_w_kernel<<<64, 256, 0, stream>>>(W_node, Bsp);
  init_kernel<<<N_ATOMS / 32, 256, 0, stream>>>(fatoms, fbonds, aoutgraph,
                                                W_nin, W_node, HnA, base);

  const int nblk = N_ATOMS / 32;  // 3125
  for (int it = 0; it < DEPTH; ++it) {
    const float* in = (it & 1) ? HnB : HnA;
    float* o = (it & 1) ? HnA : HnB;
    fused_kernel<<<nblk, 256, 0, stream>>>(in, base, Bsp, aoutgraph,
                                           all_bonds, o);
  }
  // DEPTH even -> final Hn is in HnA; d_out receives the transpose.
  dim3 tgrid((N_ATOMS + 63) / 64, HIDDEN / 64);
  transpose_kernel<<<tgrid, 256, 0, stream>>>(HnA, out);
}

// Round 17
// 1928.941 us; speedup vs baseline: 1.2971x; 1.2971x over previous
//
#include <hip/hip_runtime.h>

#define N_ATOMS 100000
#define N_BONDS 200000
#define MAX_NB 6
#define HIDDEN 256
#define DEPTH 6
#define ATOM_FDIM 39
#define BOND_FDIM 11
#define WNODE_COLS (HIDDEN + BOND_FDIM)  // 267

typedef __attribute__((ext_vector_type(8))) short bf16x8;
typedef __attribute__((ext_vector_type(4))) short s16x4;
typedef __attribute__((ext_vector_type(4))) float f32x4;

__device__ __forceinline__ unsigned short f2bf(float x) {
  unsigned u = __float_as_uint(x);
  unsigned r = (u + 0x7FFFu + ((u >> 16) & 1u)) >> 16;
  return (unsigned short)r;
}
__device__ __forceinline__ float bf2f(unsigned short h) {
  return __uint_as_float(((unsigned)h) << 16);
}
// exact 3-term decomposition: x = t1 + t2 + t3 + O(2^-27 x)
__device__ __forceinline__ void split3(float x, short* s1, short* s2, short* s3) {
  unsigned short h1 = f2bf(x);
  float r1 = x - bf2f(h1);
  unsigned short h2 = f2bf(r1);
  float r2 = r1 - bf2f(h2);
  *s1 = (short)h1;
  *s2 = (short)h2;
  *s3 = (short)f2bf(r2);
}

union U4 { short s[4]; s16x4 v; };
union U8 { short s[8]; bf16x8 v; };

// ---------------------------------------------------------------------------
// split_w: one-off. Bsp[t][n][k] = term t of split3(W_node[n][k]), k<256.
// ---------------------------------------------------------------------------
__global__ __launch_bounds__(256) void split_w_kernel(
    const float* __restrict__ W, short* __restrict__ Bsp) {
  int g = blockIdx.x * 256 + threadIdx.x;  // 16384
  int n = g >> 6;
  int k4 = (g & 63) * 4;
  const float* wp = &W[(size_t)n * WNODE_COLS + k4];
  int o = n * 256 + k4;
#pragma unroll
  for (int j = 0; j < 4; ++j) {
    short a, b, c;
    split3(wp[j], &a, &b, &c);
    Bsp[o + j] = a;
    Bsp[65536 + o + j] = b;
    Bsp[131072 + o + j] = c;
  }
}

// ---------------------------------------------------------------------------
// prep_t: one-off transposed fp32 copies for the in-kernel base recompute.
// ---------------------------------------------------------------------------
__global__ __launch_bounds__(256) void prep_t_kernel(
    const float* __restrict__ W_nin, const float* __restrict__ W_node,
    float* __restrict__ Wn_t, float* __restrict__ Wf_t) {
  int n = threadIdx.x;
  for (int k = 0; k < ATOM_FDIM; ++k)
    Wn_t[k * 256 + n] = W_nin[(size_t)n * ATOM_FDIM + k];
  for (int k = 0; k < BOND_FDIM; ++k)
    Wf_t[k * 256 + n] = W_node[(size_t)n * WNODE_COLS + HIDDEN + k];
}

// ---------------------------------------------------------------------------
// init: Hn = h0 = relu(fatoms @ W_nin.T)  (fp32, normal stores -> L3)
// ---------------------------------------------------------------------------
__global__ __launch_bounds__(256) void init_kernel(
    const float* __restrict__ fatoms,
    const float* __restrict__ W_nin,
    float* __restrict__ Hn) {
  __shared__ float Wn_lds[ATOM_FDIM * 256];   // [k][n]
  __shared__ float fa_lds[32 * 41];           // [atom][k]
  int tid = threadIdx.x;
  int a0 = blockIdx.x * 32;

  for (int k = 0; k < ATOM_FDIM; ++k)
    Wn_lds[k * 256 + tid] = W_nin[tid * ATOM_FDIM + k];
  {
    int a_l = tid >> 3, j8 = tid & 7;
#pragma unroll
    for (int jj = 0; jj < 5; ++jj) {
      int k = j8 * 5 + jj;
      if (k < ATOM_FDIM)
        fa_lds[a_l * 41 + k] = fatoms[(size_t)(a0 + a_l) * ATOM_FDIM + k];
    }
  }
  __syncthreads();

  int l = tid & 63, w = tid >> 6;
  f32x4 acc1[8] = {};
  for (int k = 0; k < ATOM_FDIM; ++k) {
    f32x4 wv = *(const f32x4*)&Wn_lds[k * 256 + l * 4];
#pragma unroll
    for (int ai = 0; ai < 8; ++ai) {
      float av = fa_lds[(w * 8 + ai) * 41 + k];
      acc1[ai] += wv * av;
    }
  }
#pragma unroll
  for (int ai = 0; ai < 8; ++ai) {
    size_t off = (size_t)(a0 + w * 8 + ai) * HIDDEN + l * 4;
    f32x4 h0v;
#pragma unroll
    for (int j = 0; j < 4; ++j) h0v[j] = fmaxf(acc1[ai][j], 0.f);
    *(f32x4*)&Hn[off] = h0v;
  }
}

// ---------------------------------------------------------------------------
// gather: Nsum[a] = sum_nb [b!=0] Hn[bonds[2b+1]]   (fp32)
// One wave per atom; wave reads full 1KB rows coalesced. NORMAL full-line
// stores -> Nsum L3-allocates so the gemm's A-reads are L3 hits (vs r9's NT
// round-trip through HBM). During this dispatch L3 holds Hn(102)+Nsum(102).
// ---------------------------------------------------------------------------
__global__ __launch_bounds__(256) void gather_kernel(
    const float* __restrict__ Hn,
    const int* __restrict__ aout,
    const int* __restrict__ bonds,
    float* __restrict__ Nsum) {
  int a = blockIdx.x * 4 + (threadIdx.x >> 6);
  int l = threadIdx.x & 63;
  const int* ap = &aout[(size_t)a * MAX_NB];
  f32x4 s = {0.f, 0.f, 0.f, 0.f};
#pragma unroll
  for (int nb = 0; nb < MAX_NB; ++nb) {
    int b = ap[nb];               // wave-uniform
    if (b != 0) {                 // wave-uniform branch
      int src = bonds[2 * b + 1];
      s += *(const f32x4*)&Hn[(size_t)src * HIDDEN + l * 4];
    }
  }
  *(f32x4*)&Nsum[(size_t)a * HIDDEN + l * 4] = s;  // normal, full-line
}

// ---------------------------------------------------------------------------
// gemm: Hn = relu(base + split3(Nsum) @ Wsplit.T)  -- Hn updated IN PLACE.
// base = relu(fa@Wn^T) + fbsum@Wf^T RECOMPUTED into the accumulator (no base
// array, no 102MB stream). Gather-free kernel => scattered normal stores
// merge cleanly (r9: W112) and L3-allocate Hn for the next gather.
// 64 atoms x 256 cols, 4 waves; acc[4][4]; r9 chunk pipeline (B oldest,
// A-prefetch young, sched_barrier, MFMA setprio, split+ds_write).
// ---------------------------------------------------------------------------
#define KCH 32
#define AST 40  // LDS row stride in bf16 (32 + 8 pad; 80 B, 16B-aligned)

__global__ __launch_bounds__(256, 3) void gemm_kernel(
    const float* __restrict__ Nsum,
    const short* __restrict__ Bsp,        // [3][256][256] bf16 terms
    const int* __restrict__ aout,
    const float* __restrict__ fatoms,
    const float* __restrict__ fbonds,
    const float* __restrict__ Wn_t,       // [39][256]
    const float* __restrict__ Wf_t,       // [11][256]
    float* __restrict__ Hn_out) {
  __shared__ short As[2][3][64 * AST];    // 30.7 KB
  __shared__ float fa_lds[64 * 41];       // 10.5 KB
  __shared__ float fbs_lds[64 * 12];      // 3 KB
  __shared__ int aout_lds[384];
  int tid = threadIdx.x;
  int a0 = blockIdx.x * 64;

  // stage aout + fatoms tiles (tail-clamped)
  for (int i = tid; i < 384; i += 256) {
    int a_l = i / 6, nb = i - a_l * 6;
    int ag = a0 + a_l;
    if (ag > N_ATOMS - 1) ag = N_ATOMS - 1;
    aout_lds[i] = aout[(size_t)ag * MAX_NB + nb];
  }
  {
    int a_l = tid >> 2, j4 = tid & 3;
    int ag = a0 + a_l;
    if (ag > N_ATOMS - 1) ag = N_ATOMS - 1;
#pragma unroll
    for (int jj = 0; jj < 10; ++jj) {
      int k = j4 * 10 + jj;
      if (k < ATOM_FDIM)
        fa_lds[a_l * 41 + k] = fatoms[(size_t)ag * ATOM_FDIM + k];
    }
  }
  __syncthreads();

  // fbsum (all 6 neighbors unconditionally, matching reference)
  for (int i = tid; i < 64 * 12; i += 256) {
    int a_l = i / 12, f = i - a_l * 12;
    if (f < BOND_FDIM) {
      float s = 0.f;
#pragma unroll
      for (int nb = 0; nb < MAX_NB; ++nb) {
        int b = aout_lds[a_l * MAX_NB + nb];
        s += fbonds[(size_t)b * BOND_FDIM + f];
      }
      fbs_lds[a_l * 12 + f] = s;
    }
  }

  int lane = tid & 63, w = tid >> 6;
  int lr = lane & 15, lk = lane >> 4;
  int r_a = tid >> 2, q_a = tid & 3;      // staging role: row 0..63, k-oct
  int rg = a0 + r_a;
  if (rg > N_ATOMS - 1) rg = N_ATOMS - 1;
  const float* np = &Nsum[(size_t)rg * HIDDEN + q_a * 8];
  int ao_st = r_a * AST + q_a * 8;

  // ---- issue chunk-0 A loads NOW (L3-hit); base-init hides them ----
  f32x4 g0a = *(const f32x4*)np;
  f32x4 g0b = *(const f32x4*)(np + 4);

  __syncthreads();  // fbs_lds ready

  // ---- base-init: acc = relu(fa@Wn^T) + fbsum@Wf^T ----
  f32x4 acc[4][4] = {};
#pragma unroll 4
  for (int k = 0; k < ATOM_FDIM; ++k) {
    float wv[4];
#pragma unroll
    for (int n = 0; n < 4; ++n) wv[n] = Wn_t[k * 256 + w * 64 + n * 16 + lr];
#pragma unroll
    for (int m = 0; m < 4; ++m) {
      float fav[4];
#pragma unroll
      for (int r = 0; r < 4; ++r)
        fav[r] = fa_lds[(m * 16 + lk * 4 + r) * 41 + k];
#pragma unroll
      for (int n = 0; n < 4; ++n)
#pragma unroll
        for (int r = 0; r < 4; ++r) acc[m][n][r] += fav[r] * wv[n];
    }
  }
#pragma unroll
  for (int m = 0; m < 4; ++m)
#pragma unroll
    for (int n = 0; n < 4; ++n)
#pragma unroll
      for (int r = 0; r < 4; ++r) acc[m][n][r] = fmaxf(acc[m][n][r], 0.f);
#pragma unroll
  for (int k = 0; k < BOND_FDIM; ++k) {
    float wv[4];
#pragma unroll
    for (int n = 0; n < 4; ++n) wv[n] = Wf_t[k * 256 + w * 64 + n * 16 + lr];
#pragma unroll
    for (int m = 0; m < 4; ++m) {
      float fbv[4];
#pragma unroll
      for (int r = 0; r < 4; ++r)
        fbv[r] = fbs_lds[(m * 16 + lk * 4 + r) * 12 + k];
#pragma unroll
      for (int n = 0; n < 4; ++n)
#pragma unroll
        for (int r = 0; r < 4; ++r) acc[m][n][r] += fbv[r] * wv[n];
    }
  }

  // ---- finish chunk 0: split, stage As[0] ----
  {
    U8 t1, t2, t3;
#pragma unroll
    for (int j = 0; j < 4; ++j) split3(g0a[j], &t1.s[j], &t2.s[j], &t3.s[j]);
#pragma unroll
    for (int j = 0; j < 4; ++j)
      split3(g0b[j], &t1.s[4 + j], &t2.s[4 + j], &t3.s[4 + j]);
    *(bf16x8*)&As[0][0][ao_st] = t1.v;
    *(bf16x8*)&As[0][1][ao_st] = t2.v;
    *(bf16x8*)&As[0][2][ao_st] = t3.v;
  }
  __syncthreads();

#pragma unroll
  for (int c = 0; c < 8; ++c) {
    const int cur = c & 1;
    // ---- 1. B loads chunk c (oldest in vmcnt queue, L2-hot) ----
    bf16x8 b0[4], b1[4], b2[4];
#pragma unroll
    for (int n = 0; n < 4; ++n) {
      int bo = (w * 64 + n * 16 + lr) * 256 + c * KCH + lk * 8;
      b0[n] = *(const bf16x8*)&Bsp[bo];
      b1[n] = *(const bf16x8*)&Bsp[65536 + bo];
      b2[n] = *(const bf16x8*)&Bsp[131072 + bo];
    }
    // ---- 2. linear A loads chunk c+1 (young, L3-hit, fly over MFMA) ----
    f32x4 va = {0.f, 0.f, 0.f, 0.f}, vb = {0.f, 0.f, 0.f, 0.f};
    if (c < 7) {
      const int k1 = (c + 1) * KCH;
      va = *(const f32x4*)(np + k1);
      vb = *(const f32x4*)(np + k1 + 4);
    }
    __builtin_amdgcn_sched_barrier(0);
    // ---- 3. MFMA cluster ----
    __builtin_amdgcn_s_setprio(1);
#pragma unroll
    for (int m = 0; m < 4; ++m) {
      int ao = (m * 16 + lr) * AST + lk * 8;
      bf16x8 af0 = *(const bf16x8*)&As[cur][0][ao];
      bf16x8 af1 = *(const bf16x8*)&As[cur][1][ao];
      bf16x8 af2 = *(const bf16x8*)&As[cur][2][ao];
#pragma unroll
      for (int n = 0; n < 4; ++n) {
        f32x4 cc = acc[m][n];
        cc = __builtin_amdgcn_mfma_f32_16x16x32_bf16(af0, b0[n], cc, 0, 0, 0);
        cc = __builtin_amdgcn_mfma_f32_16x16x32_bf16(af0, b1[n], cc, 0, 0, 0);
        cc = __builtin_amdgcn_mfma_f32_16x16x32_bf16(af1, b0[n], cc, 0, 0, 0);
        cc = __builtin_amdgcn_mfma_f32_16x16x32_bf16(af1, b1[n], cc, 0, 0, 0);
        cc = __builtin_amdgcn_mfma_f32_16x16x32_bf16(af0, b2[n], cc, 0, 0, 0);
        cc = __builtin_amdgcn_mfma_f32_16x16x32_bf16(af2, b0[n], cc, 0, 0, 0);
        acc[m][n] = cc;
      }
    }
    __builtin_amdgcn_s_setprio(0);
    // ---- 4. split + LDS write chunk c+1 ----
    if (c < 7) {
      U8 t1, t2, t3;
#pragma unroll
      for (int j = 0; j < 4; ++j) split3(va[j], &t1.s[j], &t2.s[j], &t3.s[j]);
#pragma unroll
      for (int j = 0; j < 4; ++j)
        split3(vb[j], &t1.s[4 + j], &t2.s[4 + j], &t3.s[4 + j]);
      *(bf16x8*)&As[cur ^ 1][0][ao_st] = t1.v;
      *(bf16x8*)&As[cur ^ 1][1][ao_st] = t2.v;
      *(bf16x8*)&As[cur ^ 1][2][ao_st] = t3.v;
      __syncthreads();
    }
  }

  // ---- epilogue: Hn_out = relu(acc) (acc already contains base) ----
  // NORMAL stores: gather-free kernel => lines merge in L2 (r9: W112 clean)
  // and L3-allocate so the next gather's Hn_in reads are L3 hits.
#pragma unroll
  for (int m = 0; m < 4; ++m) {
    int row0 = a0 + m * 16 + lk * 4;
#pragma unroll
    for (int n = 0; n < 4; ++n) {
      int col = w * 64 + n * 16 + lr;
#pragma unroll
      for (int r = 0; r < 4; ++r) {
        int row = row0 + r;
        if (row < N_ATOMS)
          Hn_out[(size_t)row * HIDDEN + col] = fmaxf(acc[m][n][r], 0.f);
      }
    }
  }
}

// ---------------------------------------------------------------------------
// transpose: out[h][a] = Hn[a][h]; 64x64 tiles; NT output stores.
// ---------------------------------------------------------------------------
__global__ __launch_bounds__(256) void transpose_kernel(
    const float* __restrict__ Hn, float* __restrict__ out) {
  __shared__ float tile[64][68];
  int a0 = blockIdx.x * 64, h0 = blockIdx.y * 64;
  int tid = threadIdx.x;
#pragma unroll
  for (int p = 0; p < 2; ++p) {
    int id = tid + p * 256;
    int r = id >> 3, c8 = (id & 7) * 8;
    int ag = a0 + r;
    if (ag > N_ATOMS - 1) ag = N_ATOMS - 1;
    const float* hp = &Hn[(size_t)ag * HIDDEN + h0 + c8];
    *(f32x4*)&tile[r][c8] = *(const f32x4*)hp;
    *(f32x4*)&tile[r][c8 + 4] = *(const f32x4*)(hp + 4);
  }
  __syncthreads();
  int h = tid >> 2, as = (tid & 3) * 16;
  size_t ob = (size_t)(h0 + h) * N_ATOMS + a0 + as;
  if (a0 + 64 <= N_ATOMS) {
#pragma unroll
    for (int q = 0; q < 4; ++q) {
      f32x4 v;
#pragma unroll
      for (int j = 0; j < 4; ++j) v[j] = tile[as + q * 4 + j][h];
      __builtin_nontemporal_store(v, (f32x4*)&out[ob + q * 4]);
    }
  } else {
    for (int j = 0; j < 16; ++j)
      if (a0 + as + j < N_ATOMS)
        __builtin_nontemporal_store(tile[as + j][h], &out[ob + j]);
  }
}

extern "C" void kernel_launch(void* const* d_in, const int* in_sizes, int n_in,
                              void* d_out, int out_size, void* d_ws, size_t ws_size,
                              hipStream_t stream) {
  const float* fatoms = (const float*)d_in[0];
  const float* fbonds = (const float*)d_in[1];
  const int* aoutgraph = (const int*)d_in[2];
  const int* all_bonds = (const int*)d_in[3];
  const float* W_nin = (const float*)d_in[4];
  const float* W_node = (const float*)d_in[5];
  float* out = (float*)d_out;

  const size_t NH = (size_t)N_ATOMS * HIDDEN;
  float* Hn = (float*)d_ws;                 // 102.4 MB (in-place update)
  short* Bsp = (short*)(Hn + NH);           // 384 KB pre-split W terms
  float* Wn_t = (float*)(Bsp + 3 * 65536);  // 40 KB
  float* Wf_t = Wn_t + ATOM_FDIM * 256;     // 11 KB
  float* Nsum = out;                        // d_out = gather-sum scratch

  split_w_kernel<<<64, 256, 0, stream>>>(W_node, Bsp);
  prep_t_kernel<<<1, 256, 0, stream>>>(W_nin, W_node, Wn_t, Wf_t);
  init_kernel<<<N_ATOMS / 32, 256, 0, stream>>>(fatoms, W_nin, Hn);

  const int nblk = (N_ATOMS + 63) / 64;  // 1563
  for (int it = 0; it < DEPTH; ++it) {
    gather_kernel<<<N_ATOMS / 4, 256, 0, stream>>>(Hn, aoutgraph, all_bonds,
                                                   Nsum);
    gemm_kernel<<<nblk, 256, 0, stream>>>(Nsum, Bsp, aoutgraph, fatoms,
                                          fbonds, Wn_t, Wf_t, Hn);
  }
  // Final Hn -> d_out (overwrites Nsum scratch).
  dim3 tgrid(nblk, HIDDEN / 64);
  transpose_kernel<<<tgrid, 256, 0, stream>>>(Hn, out);
}

// Round 18
// 1207.198 us; speedup vs baseline: 2.0726x; 1.5979x over previous
//
#include <hip/hip_runtime.h>

#define N_ATOMS 100000
#define N_BONDS 200000
#define MAX_NB 6
#define HIDDEN 256
#define DEPTH 6
#define ATOM_FDIM 39
#define BOND_FDIM 11
#define WNODE_COLS (HIDDEN + BOND_FDIM)  // 267

typedef __attribute__((ext_vector_type(8))) _Float16 f16x8;
typedef __attribute__((ext_vector_type(4))) short s16x4;
typedef __attribute__((ext_vector_type(4))) float f32x4;

// exact 2-term fp16 decomposition: x = h1 + h2 + O(2^-22 x)
// (r1 = x - (float)h1 is exact in fp32: same binade subtraction)
__device__ __forceinline__ void split2(float x, short* s1, short* s2) {
  union { _Float16 h; short s; } u1, u2;
  u1.h = (_Float16)x;
  float r1 = x - (float)u1.h;
  u2.h = (_Float16)r1;
  *s1 = u1.s;
  *s2 = u2.s;
}

union U4 { short s[4]; s16x4 v; };

// ---------------------------------------------------------------------------
// split_w: one-off. Bsp[t][n][k] = term t of split2(W_node[n][k]), k<256.
// ---------------------------------------------------------------------------
__global__ __launch_bounds__(256) void split_w_kernel(
    const float* __restrict__ W, short* __restrict__ Bsp) {
  int g = blockIdx.x * 256 + threadIdx.x;  // 16384
  int n = g >> 6;
  int k4 = (g & 63) * 4;
  const float* wp = &W[(size_t)n * WNODE_COLS + k4];
  int o = n * 256 + k4;
#pragma unroll
  for (int j = 0; j < 4; ++j) {
    short a, b;
    split2(wp[j], &a, &b);
    Bsp[o + j] = a;
    Bsp[65536 + o + j] = b;
  }
}

// ---------------------------------------------------------------------------
// init: per block of 32 atoms (256 thr):
//   Hn = h0 = relu(fatoms @ W_nin.T)   (fp32)
//   base = h0 + (sum_nb fbonds[aoutgraph]) @ W_f.T   (fp32)
// ---------------------------------------------------------------------------
__global__ __launch_bounds__(256) void init_kernel(
    const float* __restrict__ fatoms,
    const float* __restrict__ fbonds,
    const int* __restrict__ aoutgraph,
    const float* __restrict__ W_nin,
    const float* __restrict__ W_node,
    float* __restrict__ Hn,
    float* __restrict__ base) {
  __shared__ float Wn_lds[ATOM_FDIM * 256];   // [k][n]
  __shared__ float Wf_lds[BOND_FDIM * 256];   // [k][n]
  __shared__ float fa_lds[32 * 40];           // [atom][k]
  __shared__ float fs_lds[32 * 12];           // [atom][f]
  int tid = threadIdx.x;
  int a0 = blockIdx.x * 32;

  for (int k = 0; k < ATOM_FDIM; ++k)
    Wn_lds[k * 256 + tid] = W_nin[tid * ATOM_FDIM + k];
  for (int k = 0; k < BOND_FDIM; ++k)
    Wf_lds[k * 256 + tid] = W_node[tid * WNODE_COLS + HIDDEN + k];
  {
    int a_l = tid >> 3, j8 = tid & 7;
#pragma unroll
    for (int jj = 0; jj < 5; ++jj) {
      int k = j8 * 5 + jj;
      if (k < ATOM_FDIM)
        fa_lds[a_l * 40 + k] = fatoms[(size_t)(a0 + a_l) * ATOM_FDIM + k];
    }
  }
  for (int i = tid; i < 384; i += 256) {
    int a_l = i / 12, f = i - a_l * 12;
    if (f < BOND_FDIM) {
      float s = 0.f;
#pragma unroll
      for (int nb = 0; nb < MAX_NB; ++nb) {
        int b = aoutgraph[(size_t)(a0 + a_l) * MAX_NB + nb];
        s += fbonds[(size_t)b * BOND_FDIM + f];
      }
      fs_lds[a_l * 12 + f] = s;
    }
  }
  __syncthreads();

  int l = tid & 63, w = tid >> 6;
  f32x4 acc1[8] = {};
  f32x4 acc2[8] = {};
  for (int k = 0; k < ATOM_FDIM; ++k) {
    f32x4 wv = *(const f32x4*)&Wn_lds[k * 256 + l * 4];
#pragma unroll
    for (int ai = 0; ai < 8; ++ai) {
      float av = fa_lds[(w * 8 + ai) * 40 + k];
      acc1[ai] += wv * av;
    }
  }
  for (int k = 0; k < BOND_FDIM; ++k) {
    f32x4 wv = *(const f32x4*)&Wf_lds[k * 256 + l * 4];
#pragma unroll
    for (int ai = 0; ai < 8; ++ai) {
      float av = fs_lds[(w * 8 + ai) * 12 + k];
      acc2[ai] += wv * av;
    }
  }
#pragma unroll
  for (int ai = 0; ai < 8; ++ai) {
    int a_g = a0 + w * 8 + ai;
    size_t off = (size_t)a_g * HIDDEN + l * 4;
    f32x4 h0v, bs;
#pragma unroll
    for (int j = 0; j < 4; ++j) {
      float h0j = fmaxf(acc1[ai][j], 0.f);
      h0v[j] = h0j;
      bs[j] = h0j + acc2[ai][j];
    }
    *(f32x4*)&Hn[off] = h0v;
    *(f32x4*)&base[off] = bs;
  }
}

// ---------------------------------------------------------------------------
// fused iteration: Hn_out = relu(base + (sum_nb [b!=0] Hn_in[src]) @ W_h.T)
// r10 structure; arithmetic switched to fp16 2-term split (4 products/frag).
// block = 32 atoms x 256 cols; 256 thr (4 waves; wave w = 32 x cols w*64..+63).
// Issue order per chunk (pinned): B loads (L2-hot, oldest) -> gather loads
// c+1 (young, in flight over MFMA) -> MFMA -> sum/split/ds_write -> barrier.
// Cache policy (r10-proven): normal loads; Hn_out NT store preceded by base
// load (line-merge in L2 -- r12 A/B lesson).
// ---------------------------------------------------------------------------
#define KCH 32
#define AST 40  // LDS row stride in fp16 elems (32 + 8 pad; 80 B, 16B-aligned)

__global__ __launch_bounds__(256, 3) void fused_kernel(
    const float* __restrict__ Hn_in,
    const float* __restrict__ base,
    const short* __restrict__ Bsp,        // [2][256][256] fp16 terms
    const int* __restrict__ aout,
    const int* __restrict__ bonds,
    float* __restrict__ Hn_out) {
  __shared__ short As[2][2][32 * AST];    // 10.2 KB
  __shared__ int src_lds[192];
  int tid = threadIdx.x;
  int a0 = blockIdx.x * 32;

  if (tid < 192) {
    int a_l = tid / 6, nb = tid - a_l * 6;
    int b = aout[(size_t)(a0 + a_l) * MAX_NB + nb];
    src_lds[tid] = (b != 0) ? bonds[2 * b + 1] : -1;
  }
  __syncthreads();

  int lane = tid & 63, w = tid >> 6;
  int lr = lane & 15, lk = lane >> 4;
  int r_a = tid >> 3, q = tid & 7;        // staging: row 0..31, k-quad 0..7

  // per-thread gather sources as u32 byte offsets from Hn_in (saddr form)
  const char* hb = (const char*)Hn_in;
  unsigned voff[MAX_NB];
  float gw[MAX_NB];
#pragma unroll
  for (int nb = 0; nb < MAX_NB; ++nb) {
    int s = src_lds[r_a * 6 + nb];
    int sr = s >= 0 ? s : 0;
    gw[nb] = s >= 0 ? 1.f : 0.f;
    voff[nb] = (unsigned)((sr * HIDDEN + q * 4) * 4);
  }
  int ao_st = r_a * AST + q * 4;          // LDS write slot (8 B)

  f32x4 acc[2][4] = {};

  // ---- prologue: gather+split chunk 0 into As[0] ----
  {
    f32x4 v = {0.f, 0.f, 0.f, 0.f};
#pragma unroll
    for (int nb = 0; nb < MAX_NB; ++nb)
      v += *(const f32x4*)(hb + voff[nb]) * gw[nb];
    U4 t1, t2;
#pragma unroll
    for (int j = 0; j < 4; ++j) split2(v[j], &t1.s[j], &t2.s[j]);
    *(s16x4*)&As[0][0][ao_st] = t1.v;
    *(s16x4*)&As[0][1][ao_st] = t2.v;
  }
  __syncthreads();

#pragma unroll
  for (int c = 0; c < 8; ++c) {
    const int cur = c & 1;
    // ---- 1. B loads chunk c: issued FIRST -> oldest in vmcnt queue ----
    f16x8 b0[4], b1[4];
#pragma unroll
    for (int n = 0; n < 4; ++n) {
      int bo = (w * 64 + n * 16 + lr) * 256 + c * KCH + lk * 8;
      b0[n] = *(const f16x8*)&Bsp[bo];
      b1[n] = *(const f16x8*)&Bsp[65536 + bo];
    }
    // ---- 2. gather loads chunk c+1: younger, in flight over MFMA ----
    f32x4 ga[MAX_NB];
    if (c < 7) {
#pragma unroll
      for (int nb = 0; nb < MAX_NB; ++nb)
        ga[nb] = *(const f32x4*)(hb + voff[nb] + (c + 1) * KCH * 4);
    }
    __builtin_amdgcn_sched_barrier(0);
    // ---- 3. MFMA cluster: 2 m-frags x 4 n-frags x 4 products ----
    __builtin_amdgcn_s_setprio(1);
#pragma unroll
    for (int m = 0; m < 2; ++m) {
      int ao = (m * 16 + lr) * AST + lk * 8;
      f16x8 af0 = *(const f16x8*)&As[cur][0][ao];
      f16x8 af1 = *(const f16x8*)&As[cur][1][ao];
#pragma unroll
      for (int n = 0; n < 4; ++n) {
        f32x4 cc = acc[m][n];
        cc = __builtin_amdgcn_mfma_f32_16x16x32_f16(af0, b0[n], cc, 0, 0, 0);
        cc = __builtin_amdgcn_mfma_f32_16x16x32_f16(af0, b1[n], cc, 0, 0, 0);
        cc = __builtin_amdgcn_mfma_f32_16x16x32_f16(af1, b0[n], cc, 0, 0, 0);
        cc = __builtin_amdgcn_mfma_f32_16x16x32_f16(af1, b1[n], cc, 0, 0, 0);
        acc[m][n] = cc;
      }
    }
    __builtin_amdgcn_s_setprio(0);
    // ---- 4. finish gather c+1: sum, split, LDS write, barrier ----
    if (c < 7) {
      f32x4 v = {0.f, 0.f, 0.f, 0.f};
#pragma unroll
      for (int nb = 0; nb < MAX_NB; ++nb) v += ga[nb] * gw[nb];
      U4 t1, t2;
#pragma unroll
      for (int j = 0; j < 4; ++j) split2(v[j], &t1.s[j], &t2.s[j]);
      *(s16x4*)&As[cur ^ 1][0][ao_st] = t1.v;
      *(s16x4*)&As[cur ^ 1][1][ao_st] = t2.v;
      __syncthreads();
    }
  }

  // ---- epilogue: relu(base + acc) -> Hn_out (NT store; normal base load
  // precedes the store so lines merge in L2 -- r10/r12 A-B lesson) ----
#pragma unroll
  for (int m = 0; m < 2; ++m) {
    int row0 = a0 + m * 16 + lk * 4;
#pragma unroll
    for (int n = 0; n < 4; ++n) {
      int col = w * 64 + n * 16 + lr;
#pragma unroll
      for (int r = 0; r < 4; ++r) {
        size_t off = (size_t)(row0 + r) * HIDDEN + col;
        float v = fmaxf(base[off] + acc[m][n][r], 0.f);
        __builtin_nontemporal_store(v, &Hn_out[off]);
      }
    }
  }
}

// ---------------------------------------------------------------------------
// transpose: out[h][a] = Hn[a][h]; 64x64 tiles; NT output stores.
// ---------------------------------------------------------------------------
__global__ __launch_bounds__(256) void transpose_kernel(
    const float* __restrict__ Hn, float* __restrict__ out) {
  __shared__ float tile[64][68];
  int a0 = blockIdx.x * 64, h0 = blockIdx.y * 64;
  int tid = threadIdx.x;
#pragma unroll
  for (int p = 0; p < 2; ++p) {
    int id = tid + p * 256;
    int r = id >> 3, c8 = (id & 7) * 8;
    int ag = a0 + r;
    if (ag > N_ATOMS - 1) ag = N_ATOMS - 1;
    const float* hp = &Hn[(size_t)ag * HIDDEN + h0 + c8];
    *(f32x4*)&tile[r][c8] = *(const f32x4*)hp;
    *(f32x4*)&tile[r][c8 + 4] = *(const f32x4*)(hp + 4);
  }
  __syncthreads();
  int h = tid >> 2, as = (tid & 3) * 16;
  size_t ob = (size_t)(h0 + h) * N_ATOMS + a0 + as;
  if (a0 + 64 <= N_ATOMS) {
#pragma unroll
    for (int q = 0; q < 4; ++q) {
      f32x4 v;
#pragma unroll
      for (int j = 0; j < 4; ++j) v[j] = tile[as + q * 4 + j][h];
      __builtin_nontemporal_store(v, (f32x4*)&out[ob + q * 4]);
    }
  } else {
    for (int j = 0; j < 16; ++j)
      if (a0 + as + j < N_ATOMS)
        __builtin_nontemporal_store(tile[as + j][h], &out[ob + j]);
  }
}

extern "C" void kernel_launch(void* const* d_in, const int* in_sizes, int n_in,
                              void* d_out, int out_size, void* d_ws, size_t ws_size,
                              hipStream_t stream) {
  const float* fatoms = (const float*)d_in[0];
  const float* fbonds = (const float*)d_in[1];
  const int* aoutgraph = (const int*)d_in[2];
  const int* all_bonds = (const int*)d_in[3];
  const float* W_nin = (const float*)d_in[4];
  const float* W_node = (const float*)d_in[5];
  float* out = (float*)d_out;

  const size_t NH = (size_t)N_ATOMS * HIDDEN;
  float* base = (float*)d_ws;        // 102.4 MB
  float* HnA = base + NH;            // 102.4 MB
  short* Bsp = (short*)(HnA + NH);   // 256 KB pre-split W terms (2x fp16)
  float* HnB = out;                  // d_out doubles as ping-pong buffer

  split_w_kernel<<<64, 256, 0, stream>>>(W_node, Bsp);
  init_kernel<<<N_ATOMS / 32, 256, 0, stream>>>(fatoms, fbonds, aoutgraph,
                                                W_nin, W_node, HnA, base);

  const int nblk = N_ATOMS / 32;  // 3125
  for (int it = 0; it < DEPTH; ++it) {
    const float* in = (it & 1) ? HnB : HnA;
    float* o = (it & 1) ? HnA : HnB;
    fused_kernel<<<nblk, 256, 0, stream>>>(in, base, Bsp, aoutgraph,
                                           all_bonds, o);
  }
  // DEPTH even -> final Hn is in HnA; d_out receives the transpose.
  dim3 tgrid((N_ATOMS + 63) / 64, HIDDEN / 64);
  transpose_kernel<<<tgrid, 256, 0, stream>>>(HnA, out);
}